// Round 5
// baseline (124.657 us; speedup 1.0000x reference)
//
#include <hip/hip_runtime.h>
#include <math.h>

// Problem constants: B=4, N=65536, IN=2, OUT=512, C=64, H=32, W=32, W0=30
#define SIREN_W0 30.0f
#define K_REV 4.77464829275686f   // W0 / (2*pi): pre-scale so v_sin_f32 (revolutions) needs no muls

typedef float f32x4 __attribute__((ext_vector_type(4)));
typedef float f32x2 __attribute__((ext_vector_type(2)));

// ---------------------------------------------------------------------------
// Kernel 1: combinedS[pos][o] = K_REV * ( b_lin[o] + b_shift[o] + b_vshift[o]
//                 + sum_c latent[b,c,y,x]*W_shift[o,c]
//                 + sum_c v[b,c,y,x]*W_vshift[o,c] )
// Also: block 0 writes scaledW[o][i] = K_REV * W_lin[o][i]  (1024 floats).
// Both reference gathers use the same (iy,ix) -> one combined map suffices;
// b_lin is folded here so kernel 2's per-element math is fma,fma,v_sin.
// ---------------------------------------------------------------------------
__global__ __launch_bounds__(256) void build_combined(
    const float* __restrict__ latent, const float* __restrict__ v,
    const float* __restrict__ W_lin, const float* __restrict__ b_lin,
    const float* __restrict__ W_shift, const float* __restrict__ b_shift,
    const float* __restrict__ W_vshift, const float* __restrict__ b_vshift,
    float* __restrict__ combinedS, float* __restrict__ scaledW)
{
    const int t = threadIdx.x;
    if (blockIdx.x == 0) {
        // 256 threads x 4 floats = 1024 = OUT*IN
        f32x4 w = ((const f32x4*)W_lin)[t];
        f32x4 s = { w.x * K_REV, w.y * K_REV, w.z * K_REV, w.w * K_REV };
        ((f32x4*)scaledW)[t] = s;
    }

    __shared__ float featL[16][64];
    __shared__ float featV[16][64];
    const int pos0 = blockIdx.x * 16;
    const int b    = pos0 >> 10;        // 1024 positions per batch
    const int rem  = pos0 & 1023;

    const float* latBase = latent + (size_t)b * 65536 + rem;
    const float* vBase   = v      + (size_t)b * 65536 + rem;
#pragma unroll
    for (int k = 0; k < 4; ++k) {
        int e = t + k * 256;
        int c = e >> 4, p = e & 15;
        featL[p][c] = latBase[c * 1024 + p];
        featV[p][c] = vBase[c * 1024 + p];
    }
    __syncthreads();

    const int og = t & 127;   // 128 output-groups of 4
    const int pg = t >> 7;    // 2 position-groups of 8
    const int o0 = og * 4;
    const int p0 = pg * 8;

    float acc[8][4];
#pragma unroll
    for (int j = 0; j < 4; ++j) {
        float binit = b_lin[o0 + j] + b_shift[o0 + j] + b_vshift[o0 + j];
#pragma unroll
        for (int p = 0; p < 8; ++p) acc[p][j] = binit;
    }

    const f32x4* WS = (const f32x4*)(W_shift  + (size_t)o0 * 64);
    const f32x4* WV = (const f32x4*)(W_vshift + (size_t)o0 * 64);

#pragma unroll 4
    for (int c4 = 0; c4 < 16; ++c4) {
        f32x4 wS[4], wV[4];
#pragma unroll
        for (int j = 0; j < 4; ++j) {
            wS[j] = WS[j * 16 + c4];
            wV[j] = WV[j * 16 + c4];
        }
#pragma unroll
        for (int p = 0; p < 8; ++p) {
            f32x4 fL = *(const f32x4*)&featL[p0 + p][c4 * 4];
            f32x4 fV = *(const f32x4*)&featV[p0 + p][c4 * 4];
#pragma unroll
            for (int j = 0; j < 4; ++j) {
                acc[p][j] += fL.x * wS[j].x + fL.y * wS[j].y
                           + fL.z * wS[j].z + fL.w * wS[j].w
                           + fV.x * wV[j].x + fV.y * wV[j].y
                           + fV.z * wV[j].z + fV.w * wV[j].w;
            }
        }
    }

#pragma unroll
    for (int p = 0; p < 8; ++p) {
        f32x4 r = { acc[p][0] * K_REV, acc[p][1] * K_REV,
                    acc[p][2] * K_REV, acc[p][3] * K_REV };
        *(f32x4*)(combinedS + (size_t)(pos0 + p0 + p) * 512 + o0) = r;
    }
}

// v_sin_f32: D = sin(S0 * 2pi), input in revolutions. Args here are within
// +-32 rev, well inside HW range; same HW sin path __sinf used (absmax 3.9e-3).
#define SIN_REV(dst, src) asm("v_sin_f32 %0, %1" : "=v"(dst) : "v"(src))

// ---------------------------------------------------------------------------
// Kernel 2: out[point,o] = sin(2pi * (xv.x*sW[o][0] + xv.y*sW[o][1] + cS[o]))
// 32 threads per point; 4 float4 chunks per thread (64 B stored).
// Per element: fma, fma, v_sin -- all constants pre-folded by kernel 1.
// XCD-aware mapping kept from R3 (neutral, zero-cost, preserves L2 locality).
// ---------------------------------------------------------------------------
__global__ __launch_bounds__(256) void siren_out(
    const float* __restrict__ x, const float* __restrict__ W_lin,
    const float* __restrict__ b_lin, const float* __restrict__ combinedS,
    const float* __restrict__ scaledW, float* __restrict__ out)
{
    const int bid = blockIdx.x;
    const int xcd = bid & 7;
    const int idx = bid >> 3;
    const int pb  = ((xcd >> 1) << 13) + ((xcd & 1) << 12) + idx;

    const int tid   = pb * 256 + threadIdx.x;
    const int point = tid >> 5;
    const int lane  = tid & 31;
    const int b     = point >> 16;

    const f32x2 xv = *(const f32x2*)(x + (size_t)point * 2);

    // coordinates from UNscaled first two rows of W_lin / b_lin
    const f32x4 wl = *(const f32x4*)W_lin;
    const f32x2 bl = *(const f32x2*)b_lin;
    const float h0 = xv.x * wl.x + xv.y * wl.y + bl.x;
    const float h1 = xv.x * wl.z + xv.y * wl.w + bl.y;

    const float fx = (h0 + 1.0f) * 0.5f * 31.0f;
    const float fy = (h1 + 1.0f) * 0.5f * 31.0f;
    int ix = (int)rintf(fx); ix = ix < 0 ? 0 : (ix > 31 ? 31 : ix);
    int iy = (int)rintf(fy); iy = iy < 0 ? 0 : (iy > 31 ? 31 : iy);

    const f32x4* crow =
        (const f32x4*)(combinedS + (size_t)(((b << 5) + iy) * 32 + ix) * 512);
    const f32x4* SW = (const f32x4*)scaledW;
    f32x4* orow = ((f32x4*)out) + (size_t)point * 128;

#pragma unroll
    for (int k = 0; k < 4; ++k) {
        const int chunk = lane + k * 32;
        const f32x4 c4 = crow[chunk];
        const f32x4 wA = SW[chunk * 2];
        const f32x4 wB = SW[chunk * 2 + 1];

        const float a0 = xv.x * wA.x + xv.y * wA.y + c4.x;
        const float a1 = xv.x * wA.z + xv.y * wA.w + c4.y;
        const float a2 = xv.x * wB.x + xv.y * wB.y + c4.z;
        const float a3 = xv.x * wB.z + xv.y * wB.w + c4.w;

        f32x4 r;
        SIN_REV(r.x, a0);
        SIN_REV(r.y, a1);
        SIN_REV(r.z, a2);
        SIN_REV(r.w, a3);

        __builtin_nontemporal_store(r, orow + chunk);
    }
}

extern "C" void kernel_launch(void* const* d_in, const int* in_sizes, int n_in,
                              void* d_out, int out_size, void* d_ws, size_t ws_size,
                              hipStream_t stream) {
    const float* x        = (const float*)d_in[0];
    const float* latent   = (const float*)d_in[1];
    const float* v        = (const float*)d_in[2];
    const float* W_lin    = (const float*)d_in[3];
    const float* b_lin    = (const float*)d_in[4];
    const float* W_shift  = (const float*)d_in[5];
    const float* b_shift  = (const float*)d_in[6];
    const float* W_vshift = (const float*)d_in[7];
    const float* b_vshift = (const float*)d_in[8];
    float* out       = (float*)d_out;
    float* combinedS = (float*)d_ws;                       // 8 MiB
    float* scaledW   = (float*)((char*)d_ws + (8u << 20)); // +4 KiB

    build_combined<<<256, 256, 0, stream>>>(latent, v, W_lin, b_lin,
                                            W_shift, b_shift, W_vshift, b_vshift,
                                            combinedS, scaledW);

    siren_out<<<32768, 256, 0, stream>>>(x, W_lin, b_lin, combinedS, scaledW, out);
}